// Round 5
// baseline (396.756 us; speedup 1.0000x reference)
//
#include <hip/hip_runtime.h>
#include <hip/hip_bf16.h>

// Problem constants (fixed by reference)
#define Bn 16
#define Tn 64
#define Nn 256
#define Dn 64
#define TDn 128   // 2*D

typedef __bf16 bf16x8 __attribute__((ext_vector_type(8)));
typedef __bf16 bf16x4 __attribute__((ext_vector_type(4)));
typedef __bf16 bf16x2 __attribute__((ext_vector_type(2)));
typedef float  f32x4  __attribute__((ext_vector_type(4)));

#define QSCALE 0.35355339059327373f   // 1/sqrt(8), folded into q at phase-2 epilogue

__device__ __forceinline__ float geluf(float x) {
    // tanh-form GELU: 0.5x(1+tanh(0.79788456(x+0.044715x^3))) = x*e/(e+1), e=exp(2u).
    // Max |dev| vs exact erf-GELU ~1e-3 (absmax slack is 0.041). ~9 VALU inst vs ~30 for erff.
    const float x2 = x * x;
    const float u  = x * __builtin_fmaf(0.0356774081f, x2, 0.7978845608f); // 0.79788456*(x+0.044715x^3)
    const float e  = __expf(2.0f * u);
    return x - __fdividef(x, e + 1.0f);
}

// ---- Kernel 1: convert all weights fp32 -> bf16 into d_ws (runs every launch; ws re-poisoned) ----
// ws layout (bf16): [0,24576) Wqkv rows 0-63=W12,64-127=W13,128-191=W14 (row=128 k)
//                   [24576,28672) W15 [64][64]; [28672,32768) W16 [64][64]
__global__ void convert_weights(const float* __restrict__ W12, const float* __restrict__ W13,
                                const float* __restrict__ W14, const float* __restrict__ W15,
                                const float* __restrict__ W16, __bf16* __restrict__ ws)
{
    const int i = blockIdx.x * 256 + threadIdx.x;   // 0..32767
    float v;
    if      (i < 8192)  v = W12[i];
    else if (i < 16384) v = W13[i - 8192];
    else if (i < 24576) v = W14[i - 16384];
    else if (i < 28672) v = W15[i - 24576];
    else                v = W16[i - 28672];
    ws[i] = (__bf16)v;
}

// ---- Kernel 2: fused block per (b,n); 256 threads = 4 waves; MFMA everywhere ----
// LDS 45,056 B -> 3 blocks/CU.
__global__ __launch_bounds__(256, 3)
void tam_fused(const float* __restrict__ X,
               const float* __restrict__ STE,
               const float* __restrict__ b12, const float* __restrict__ b13,
               const float* __restrict__ b14, const float* __restrict__ b15,
               const float* __restrict__ b16,
               const __bf16* __restrict__ Wb,   // converted weights in ws
               float* __restrict__ Out)
{
    // Carved LDS: region0 [0,17408) = Hs [64][136]bf16 (phases 1-2), then Ss [64][68]fp32 /
    //             Pb bf16 (stride 136) in phase 3. qs @17408, ks @26624, vt @35840 (each [64][72]bf16).
    __shared__ __align__(16) char smem[45056];
    __bf16 (*Hs)[136] = reinterpret_cast<__bf16 (*)[136]>(smem);
    float  (*Ss)[68]  = reinterpret_cast<float  (*)[68]>(smem);
    __bf16 *Pb        = reinterpret_cast<__bf16*>(smem);                  // row stride 136
    __bf16 (*qs)[72]  = reinterpret_cast<__bf16 (*)[72]>(smem + 17408);   // q -> attn out O
    __bf16 (*ks)[72]  = reinterpret_cast<__bf16 (*)[72]>(smem + 26624);   // k -> MLP hidden
    __bf16 (*vt)[72]  = reinterpret_cast<__bf16 (*)[72]>(smem + 35840);   // v TRANSPOSED [col][t]

    const int bn   = blockIdx.x;
    const int b    = bn >> 8;     // / Nn
    const int n    = bn & 255;    // % Nn
    const int tid  = threadIdx.x;
    const int lane = tid & 63;
    const int wv   = __builtin_amdgcn_readfirstlane(tid >> 6);
    const int cl   = lane & 15;          // MFMA col / A-row in tile
    const int quad = lane >> 4;
    const int kb   = quad * 8;           // MFMA k-offset
    const int m0   = wv * 16;            // this wave's row-tile

    const __bf16* Wqkv = Wb;             // [192][128]
    const __bf16* W15b = Wb + 24576;     // [64][64]
    const __bf16* W16b = Wb + 28672;     // [64][64]

    // ---------------- Phase 1: stage H = concat(X, STE) row-major, fp32 -> bf16 ----------------
    {
        const size_t base = ((size_t)b * Tn * Nn + n) * Dn;
        for (int t = wv; t < Tn; t += 4) {
            const size_t rb = base + (size_t)t * (Nn * Dn);
            const float2 v2 = (lane < 32)
                ? reinterpret_cast<const float2*>(X + rb)[lane]
                : reinterpret_cast<const float2*>(STE + rb)[lane - 32];
            bf16x2 p; p[0] = (__bf16)v2.x; p[1] = (__bf16)v2.y;
            *reinterpret_cast<bf16x2*>(&Hs[t][2 * lane]) = p;
        }
    }
    __syncthreads();

    // ---------------- Phase 2: qkv = gelu(H @ Wqkv^T + b) via MFMA ----------------
    // q scaled by 1/sqrt(8) here; v stored transposed for PV B-frags.
    {
        bf16x8 af[4];
        #pragma unroll
        for (int kk = 0; kk < 4; ++kk)
            af[kk] = *reinterpret_cast<const bf16x8*>(&Hs[m0 + cl][kk * 32 + kb]);

        #pragma unroll 4
        for (int nt = 0; nt < 12; ++nt) {
            const int n0 = nt * 16;
            f32x4 acc = {0.f, 0.f, 0.f, 0.f};
            #pragma unroll
            for (int kk = 0; kk < 4; ++kk) {
                const bf16x8 bf = *reinterpret_cast<const bf16x8*>(
                    &Wqkv[(n0 + cl) * TDn + kk * 32 + kb]);
                acc = __builtin_amdgcn_mfma_f32_16x16x32_bf16(af[kk], bf, acc, 0, 0, 0);
            }
            const float bias = (n0 < 64) ? b12[n0 + cl]
                             : (n0 < 128) ? b13[n0 - 64 + cl]
                                          : b14[n0 - 128 + cl];
            const int row0 = m0 + quad * 4;
            float gv[4];
            #pragma unroll
            for (int r = 0; r < 4; ++r) gv[r] = geluf(acc[r] + bias);
            if (n0 < 64) {
                #pragma unroll
                for (int r = 0; r < 4; ++r) qs[row0 + r][n0 + cl] = (__bf16)(gv[r] * QSCALE);
            } else if (n0 < 128) {
                #pragma unroll
                for (int r = 0; r < 4; ++r) ks[row0 + r][n0 - 64 + cl] = (__bf16)gv[r];
            } else {
                bf16x4 p4;
                #pragma unroll
                for (int r = 0; r < 4; ++r) p4[r] = (__bf16)gv[r];
                *reinterpret_cast<bf16x4*>(&vt[n0 - 128 + cl][row0]) = p4;  // transposed store
            }
        }
    }
    __syncthreads();

    // ---------------- Phase 3: attention per head via MFMA + batch softmax ----------------
    // Per head h: (a) QK^T lower-triangle 16x16 tiles (K padded 8->32), S fp32 -> Ss;
    //             (b) barrier; batch softmax (thread = row x quarter, shfl_xor reduce),
    //                 normalized P bf16 -> Pb (same region, own-wave rows);
    //             (c) PV MFMA (A = own rows of Pb; B = vt contiguous), O -> qs cols h*8..+8;
    //             (d) barrier before next head's Ss overwrite.
    {
        // lower-triangle tile list; wave w takes jobs w, w+4, w+8 -> 3,3,2,2
        const int JM[10] = {0, 1, 1, 2, 2, 2, 3, 3, 3, 3};
        const int JN[10] = {0, 0, 1, 0, 1, 2, 0, 1, 2, 3};
        const int r_sm   = tid >> 2;        // softmax row 0..63 (wave w owns rows 16w..16w+15)
        const int cq     = tid & 3;         // col quarter
        const int s0     = cq * 16;

        for (int h = 0; h < 8; ++h) {
            const int hc = h * 8;
            // (a) QK^T tiles
            for (int jj = wv; jj < 10; jj += 4) {
                const int mt = JM[jj], nt = JN[jj];
                bf16x8 aq = {}, bk = {};
                if (quad == 0) {   // only k=0..7 valid (K padded to 32)
                    aq = *reinterpret_cast<const bf16x8*>(&qs[mt * 16 + cl][hc]);
                    bk = *reinterpret_cast<const bf16x8*>(&ks[nt * 16 + cl][hc]);
                }
                f32x4 acc = {0.f, 0.f, 0.f, 0.f};
                acc = __builtin_amdgcn_mfma_f32_16x16x32_bf16(aq, bk, acc, 0, 0, 0);
                #pragma unroll
                for (int r = 0; r < 4; ++r)
                    Ss[mt * 16 + quad * 4 + r][nt * 16 + cl] = acc[r];
            }
            __syncthreads();

            // (b) batch softmax over row r_sm, cols [s0, s0+16)
            {
                float sv[16];
                const f32x4* rp = reinterpret_cast<const f32x4*>(&Ss[r_sm][s0]);
                #pragma unroll
                for (int i4 = 0; i4 < 4; ++i4) {
                    const f32x4 x = rp[i4];
                    #pragma unroll
                    for (int k = 0; k < 4; ++k) sv[i4 * 4 + k] = x[k];
                }
                float mx = -3.0e38f;
                #pragma unroll
                for (int i = 0; i < 16; ++i)
                    if (s0 + i <= r_sm) mx = fmaxf(mx, sv[i]);
                mx = fmaxf(mx, __shfl_xor(mx, 1));
                mx = fmaxf(mx, __shfl_xor(mx, 2));
                float l = 0.0f, p[16];
                #pragma unroll
                for (int i = 0; i < 16; ++i) {
                    p[i] = (s0 + i <= r_sm) ? __expf(sv[i] - mx) : 0.0f;
                    l += p[i];
                }
                l += __shfl_xor(l, 1);
                l += __shfl_xor(l, 2);
                const float inv = __fdividef(1.0f, l);
                bf16x8 w0, w1;
                #pragma unroll
                for (int i = 0; i < 8; ++i) {
                    w0[i] = (__bf16)(p[i] * inv);
                    w1[i] = (__bf16)(p[8 + i] * inv);
                }
                *reinterpret_cast<bf16x8*>(&Pb[r_sm * 136 + s0])     = w0;
                *reinterpret_cast<bf16x8*>(&Pb[r_sm * 136 + s0 + 8]) = w1;
            }

            // (c) PV: rows m0..m0+15 (own wave's P rows -> no barrier needed)
            {
                const bf16x8 a0 = *reinterpret_cast<const bf16x8*>(&Pb[(m0 + cl) * 136 + kb]);
                const bf16x8 a1 = *reinterpret_cast<const bf16x8*>(&Pb[(m0 + cl) * 136 + 32 + kb]);
                const int vr = hc + (cl & 7);   // clamp: cols 8-15 duplicate (discarded)
                const bf16x8 v0 = *reinterpret_cast<const bf16x8*>(&vt[vr][kb]);
                const bf16x8 v1 = *reinterpret_cast<const bf16x8*>(&vt[vr][32 + kb]);
                f32x4 acc = {0.f, 0.f, 0.f, 0.f};
                acc = __builtin_amdgcn_mfma_f32_16x16x32_bf16(a0, v0, acc, 0, 0, 0);
                acc = __builtin_amdgcn_mfma_f32_16x16x32_bf16(a1, v1, acc, 0, 0, 0);
                if (cl < 8) {
                    #pragma unroll
                    for (int r = 0; r < 4; ++r)
                        qs[m0 + quad * 4 + r][hc + cl] = (__bf16)acc[r];
                }
            }
            __syncthreads();   // (d) protect Ss/Pb + qs-col handoff before next head
        }
    }

    // ---------------- Phase 4a: hidden = gelu(O @ W15^T + b15) -> ks (MFMA) ----------------
    // A rows = own wave's rows (written by own wave's PV); ks writes own rows -> no extra barrier.
    {
        const bf16x8 a0 = *reinterpret_cast<const bf16x8*>(&qs[m0 + cl][kb]);
        const bf16x8 a1 = *reinterpret_cast<const bf16x8*>(&qs[m0 + cl][32 + kb]);
        #pragma unroll
        for (int nt = 0; nt < 4; ++nt) {
            const int n0 = nt * 16;
            f32x4 acc = {0.f, 0.f, 0.f, 0.f};
            const bf16x8 bf0 = *reinterpret_cast<const bf16x8*>(&W15b[(n0 + cl) * Dn + kb]);
            acc = __builtin_amdgcn_mfma_f32_16x16x32_bf16(a0, bf0, acc, 0, 0, 0);
            const bf16x8 bf1 = *reinterpret_cast<const bf16x8*>(&W15b[(n0 + cl) * Dn + 32 + kb]);
            acc = __builtin_amdgcn_mfma_f32_16x16x32_bf16(a1, bf1, acc, 0, 0, 0);
            const float bias = b15[n0 + cl];
            #pragma unroll
            for (int r = 0; r < 4; ++r)
                ks[m0 + quad * 4 + r][n0 + cl] = (__bf16)geluf(acc[r] + bias);
        }
    }

    // ---------------- Phase 4b: out = hidden @ W16^T + b16 -> global fp32 ----------------
    {
        const bf16x8 a0 = *reinterpret_cast<const bf16x8*>(&ks[m0 + cl][kb]);
        const bf16x8 a1 = *reinterpret_cast<const bf16x8*>(&ks[m0 + cl][32 + kb]);
        #pragma unroll
        for (int nt = 0; nt < 4; ++nt) {
            const int n0 = nt * 16;
            f32x4 acc = {0.f, 0.f, 0.f, 0.f};
            const bf16x8 bf0 = *reinterpret_cast<const bf16x8*>(&W16b[(n0 + cl) * Dn + kb]);
            acc = __builtin_amdgcn_mfma_f32_16x16x32_bf16(a0, bf0, acc, 0, 0, 0);
            const bf16x8 bf1 = *reinterpret_cast<const bf16x8*>(&W16b[(n0 + cl) * Dn + 32 + kb]);
            acc = __builtin_amdgcn_mfma_f32_16x16x32_bf16(a1, bf1, acc, 0, 0, 0);
            const float bias = b16[n0 + cl];
            #pragma unroll
            for (int r = 0; r < 4; ++r) {
                const int row = m0 + quad * 4 + r;
                Out[((size_t)(b * Tn + row) * Nn + n) * Dn + n0 + cl] = acc[r] + bias;
            }
        }
    }
}

extern "C" void kernel_launch(void* const* d_in, const int* in_sizes, int n_in,
                              void* d_out, int out_size, void* d_ws, size_t ws_size,
                              hipStream_t stream)
{
    (void)in_sizes; (void)n_in; (void)out_size; (void)ws_size;
    const float* X   = (const float*)d_in[0];
    const float* STE = (const float*)d_in[1];
    const float* W12 = (const float*)d_in[2];
    const float* b12 = (const float*)d_in[3];
    const float* W13 = (const float*)d_in[4];
    const float* b13 = (const float*)d_in[5];
    const float* W14 = (const float*)d_in[6];
    const float* b14 = (const float*)d_in[7];
    const float* W15 = (const float*)d_in[8];
    const float* b15 = (const float*)d_in[9];
    const float* W16 = (const float*)d_in[10];
    const float* b16 = (const float*)d_in[11];
    float* Out = (float*)d_out;
    __bf16* ws = (__bf16*)d_ws;   // needs 65,536 B

    hipLaunchKernelGGL(convert_weights, dim3(128), dim3(256), 0, stream,
                       W12, W13, W14, W15, W16, ws);
    hipLaunchKernelGGL(tam_fused, dim3(Bn * Nn), dim3(256), 0, stream,
                       X, STE, b12, b13, b14, b15, b16, ws, Out);
}